// Round 1
// baseline (479.336 us; speedup 1.0000x reference)
//
#include <hip/hip_runtime.h>
#include <math.h>

// GradientLayer: 4->128->128->128->5 tanh MLP; per-sample Jacobian (5x4) and
// Hessians of outputs 0 and 4 (4x4), combined into 17 output arrays.
// Strategy: 1 wave per sample. LDS holds 15 vectors x 128 (primal + 4 first-order
// tangents + 10 second-order tangent pairs). Each lane owns hidden units 2t,2t+1.

namespace {

constexpr int HID = 128;

struct OSpec {
    int base, mul, off;      // out[base*nb + b*mul + off]
    int a0, a1, a2, m;       // term1 = s1*(c[a0]+c[a1]+c[a2])*c[m]
    int b0, b1, b2, m2;      // term2 = s2*(c[b0]+c[b1]+c[b2])*c[m2]
    float s1, s2;
};

// comb[] indices: 0..4 = o_k (n, v1,v2,v3, Fi); J[k][d] = comb[5+5d+k];
// Hn[pair p] = comb[25+p]; HFi[pair p] = comb[35+p]; comb[45]=0, comb[46]=1.
__constant__ OSpec g_ospec[38] = {
    {0,1,0,   0,45,45,46, 45,45,45,46, 1.f,0.f},   // n
    {1,1,0,   5,45,45,46, 45,45,45,46, 1.f,0.f},   // n_t
    {2,3,0,  10,45,45,46, 45,45,45,46, 1.f,0.f},   // n_grd[0]
    {2,3,1,  15,45,45,46, 45,45,45,46, 1.f,0.f},
    {2,3,2,  20,45,45,46, 45,45,45,46, 1.f,0.f},
    {5,3,0,   1,45,45, 0, 45,45,45,46, 1.f,0.f},   // j = n*v
    {5,3,1,   2,45,45, 0, 45,45,45,46, 1.f,0.f},
    {5,3,2,   3,45,45, 0, 45,45,45,46, 1.f,0.f},
    {8,3,0,  10,15,20, 1, 11,16,21, 0, 1.f,1.f},   // j_div
    {8,3,1,  10,15,20, 2, 12,17,22, 0, 1.f,1.f},
    {8,3,2,  10,15,20, 3, 13,18,23, 0, 1.f,1.f},
    {11,1,0,  4,45,45,46, 45,45,45,46, 1.f,0.f},   // Fi
    {12,3,0, 14,45,45,46, 45,45,45,46, 1.f,0.f},   // Fi_grd
    {12,3,1, 19,45,45,46, 45,45,45,46, 1.f,0.f},
    {12,3,2, 24,45,45,46, 45,45,45,46, 1.f,0.f},
    {15,4,0, 36,37,38,46, 45,45,45,46, 1.f,0.f},   // Fi_lap[d] = sum_e HFi[d][1..3]
    {15,4,1, 39,40,41,46, 45,45,45,46, 1.f,0.f},
    {15,4,2, 40,42,43,46, 45,45,45,46, 1.f,0.f},
    {15,4,3, 41,43,44,46, 45,45,45,46, 1.f,0.f},
    {19,3,0,  1,45,45,46, 45,45,45,46, 1.f,0.f},   // v
    {19,3,1,  2,45,45,46, 45,45,45,46, 1.f,0.f},
    {19,3,2,  3,45,45,46, 45,45,45,46, 1.f,0.f},
    {22,1,0,  5,45,45,46, 45,45,45,46, 1.f,0.f},   // v_t
    {23,3,0,  1,45,45,10, 45,45,45,46, 1.f,0.f},   // v_adv[d] = v[d]*J[0][1+d]
    {23,3,1,  2,45,45,15, 45,45,45,46, 1.f,0.f},
    {23,3,2,  3,45,45,20, 45,45,45,46, 1.f,0.f},
    {26,1,0, 26,30,33,46, 45,45,45,46, 1.f,0.f},   // v_lap = Hn01+Hn12+Hn23
    {27,3,0, 29,30,31,46, 45,45,45,46, 1.f,0.f},   // v_div_grd
    {27,3,1, 30,32,33,46, 45,45,45,46, 1.f,0.f},
    {27,3,2, 31,33,34,46, 45,45,45,46, 1.f,0.f},
    {30,1,0,  0,45,45,46, 45,45,45,46, 2.f,0.f},   // ro = 2n
    {31,1,0,  5,45,45,46, 45,45,45,46, 2.f,0.f},   // ro_t
    {32,3,0, 10,45,45,46, 45,45,45,46, 2.f,0.f},   // ro_grd
    {32,3,1, 15,45,45,46, 45,45,45,46, 2.f,0.f},
    {32,3,2, 20,45,45,46, 45,45,45,46, 2.f,0.f},
    {35,3,0, 10,15,20, 1, 11,16,21, 0, 2.f,2.f},   // rov_div = 2*j_div
    {35,3,1, 10,15,20, 2, 12,17,22, 0, 2.f,2.f},
    {35,3,2, 10,15,20, 3, 13,18,23, 0, 2.f,2.f},
};

__device__ __forceinline__ float selc(const float4& a, int ii) {
    return (ii == 0) ? a.x : (ii == 1) ? a.y : (ii == 2) ? a.z : a.w;
}

__global__ __launch_bounds__(256) void mlp_pde_kernel(
    const float* __restrict__ x,
    const float* __restrict__ W0, const float* __restrict__ b0,
    const float* __restrict__ W1, const float* __restrict__ b1,
    const float* __restrict__ W2, const float* __restrict__ b2,
    const float* __restrict__ W3, const float* __restrict__ b3,
    float* __restrict__ out, int nb)
{
    // second-derivative pair enumeration (d<=e)
    constexpr int PD[10] = {0,0,0,0,1,1,1,2,2,3};
    constexpr int PE[10] = {0,1,2,3,1,2,3,2,3,3};

    __shared__ float lds[4][1920];           // per-wave private region
    const int wave = threadIdx.x >> 6;
    const int lane = threadIdx.x & 63;
    float* buf = lds[wave];
    int b = blockIdx.x * 4 + wave;
    if (b >= nb) b = nb - 1;                 // duplicate work; same value stored (benign)
    const int j0 = lane * 2;

    // ---------------- layer 0 (4 -> 128) ----------------
    const float4 xv = *reinterpret_cast<const float4*>(x + 4 * b);
    float w0d[4][2];
    #pragma unroll
    for (int d = 0; d < 4; ++d) {
        float2 w = *reinterpret_cast<const float2*>(W0 + d * HID + j0);
        w0d[d][0] = w.x; w0d[d][1] = w.y;
    }
    const float2 bb0 = *reinterpret_cast<const float2*>(b0 + j0);

    float val[15][2];
    #pragma unroll
    for (int jj = 0; jj < 2; ++jj) {
        float z = ((jj == 0) ? bb0.x : bb0.y)
                + xv.x * w0d[0][jj] + xv.y * w0d[1][jj]
                + xv.z * w0d[2][jj] + xv.w * w0d[3][jj];
        float h = tanhf(z);
        float s = 1.f - h * h;
        val[0][jj] = h;
        #pragma unroll
        for (int d = 0; d < 4; ++d) val[1 + d][jj] = s * w0d[d][jj];
        #pragma unroll
        for (int p = 0; p < 10; ++p)
            val[5 + p][jj] = -2.f * h * s * w0d[PD[p]][jj] * w0d[PE[p]][jj];
    }
    #pragma unroll
    for (int v = 0; v < 15; ++v)
        *reinterpret_cast<float2*>(&buf[v * HID + j0]) = make_float2(val[v][0], val[v][1]);
    __syncthreads();

    // ---------------- layers 1,2 (128 -> 128) ----------------
    const float* Ws[2] = {W1, W2};
    const float* bs[2] = {b1, b2};
    #pragma unroll 1
    for (int layer = 0; layer < 2; ++layer) {
        const float* __restrict__ W = Ws[layer];
        float acc[15][2];
        #pragma unroll
        for (int v = 0; v < 15; ++v) { acc[v][0] = 0.f; acc[v][1] = 0.f; }

        for (int i4 = 0; i4 < HID / 4; ++i4) {
            float4 a[15];
            #pragma unroll
            for (int v = 0; v < 15; ++v)
                a[v] = *reinterpret_cast<const float4*>(&buf[v * HID + i4 * 4]);
            #pragma unroll
            for (int ii = 0; ii < 4; ++ii) {
                float2 w = *reinterpret_cast<const float2*>(W + (i4 * 4 + ii) * HID + j0);
                #pragma unroll
                for (int v = 0; v < 15; ++v) {
                    float av = selc(a[v], ii);
                    acc[v][0] = fmaf(av, w.x, acc[v][0]);
                    acc[v][1] = fmaf(av, w.y, acc[v][1]);
                }
            }
        }

        const float2 bbv = *reinterpret_cast<const float2*>(bs[layer] + j0);
        #pragma unroll
        for (int jj = 0; jj < 2; ++jj) {
            float z = acc[0][jj] + ((jj == 0) ? bbv.x : bbv.y);
            float h = tanhf(z);
            float s = 1.f - h * h;
            val[0][jj] = h;
            float u[4];
            #pragma unroll
            for (int d = 0; d < 4; ++d) { u[d] = acc[1 + d][jj]; val[1 + d][jj] = s * u[d]; }
            #pragma unroll
            for (int p = 0; p < 10; ++p)
                val[5 + p][jj] = -2.f * h * s * u[PD[p]] * u[PE[p]] + s * acc[5 + p][jj];
        }
        __syncthreads();   // all reads of buf complete in all waves
        if (layer == 0) {
            #pragma unroll
            for (int v = 0; v < 15; ++v)
                *reinterpret_cast<float2*>(&buf[v * HID + j0]) = make_float2(val[v][0], val[v][1]);
            __syncthreads();
        }
    }

    // ---------------- output layer: 45 dot-products with W3 columns ----------------
    float w3r[2][5];
    #pragma unroll
    for (int k = 0; k < 5; ++k) {
        w3r[0][k] = W3[j0 * 5 + k];
        w3r[1][k] = W3[(j0 + 1) * 5 + k];
    }
    float part[45];
    #pragma unroll
    for (int k = 0; k < 5; ++k)
        part[k] = val[0][0] * w3r[0][k] + val[0][1] * w3r[1][k];
    #pragma unroll
    for (int d = 0; d < 4; ++d) {
        #pragma unroll
        for (int k = 0; k < 5; ++k)
            part[5 + 5 * d + k] = val[1 + d][0] * w3r[0][k] + val[1 + d][1] * w3r[1][k];
    }
    #pragma unroll
    for (int p = 0; p < 10; ++p) {
        part[25 + p] = val[5 + p][0] * w3r[0][0] + val[5 + p][1] * w3r[1][0];
        part[35 + p] = val[5 + p][0] * w3r[0][4] + val[5 + p][1] * w3r[1][4];
    }

    // cross-lane reduce: halves first (register), then LDS transpose-reduce
    #pragma unroll
    for (int c = 0; c < 45; ++c) part[c] += __shfl_xor(part[c], 32, 64);

    float* pbuf = buf;                       // reuse: [32][52]
    if (lane < 32) {
        #pragma unroll
        for (int q = 0; q < 11; ++q)
            *reinterpret_cast<float4*>(&pbuf[lane * 52 + q * 4]) =
                make_float4(part[4 * q], part[4 * q + 1], part[4 * q + 2], part[4 * q + 3]);
        pbuf[lane * 52 + 44] = part[44];
    }
    __syncthreads();

    float* comb = buf + 32 * 52;             // 48 slots (1664..1711 < 1920)
    if (lane < 47) {
        float t;
        if (lane < 45) {
            t = 0.f;
            for (int l = 0; l < 32; ++l) t += pbuf[l * 52 + lane];
            if (lane < 5) t += b3[lane];
        } else {
            t = (lane == 46) ? 1.f : 0.f;    // comb[45]=0, comb[46]=1
        }
        comb[lane] = t;
    }
    __syncthreads();

    // ---------------- table-driven epilogue: 38 outputs per sample ----------------
    if (lane < 38) {
        OSpec sp = g_ospec[lane];
        float t1 = (comb[sp.a0] + comb[sp.a1] + comb[sp.a2]) * comb[sp.m] * sp.s1;
        float t2 = (comb[sp.b0] + comb[sp.b1] + comb[sp.b2]) * comb[sp.m2] * sp.s2;
        out[sp.base * nb + b * sp.mul + sp.off] = t1 + t2;
    }
}

} // namespace

extern "C" void kernel_launch(void* const* d_in, const int* in_sizes, int n_in,
                              void* d_out, int out_size, void* d_ws, size_t ws_size,
                              hipStream_t stream) {
    const float* x  = (const float*)d_in[0];
    const float* W0 = (const float*)d_in[1];
    const float* b0 = (const float*)d_in[2];
    const float* W1 = (const float*)d_in[3];
    const float* b1 = (const float*)d_in[4];
    const float* W2 = (const float*)d_in[5];
    const float* b2 = (const float*)d_in[6];
    const float* W3 = (const float*)d_in[7];
    const float* b3 = (const float*)d_in[8];
    float* out = (float*)d_out;

    const int nb = in_sizes[0] / 4;          // 32768
    const int blocks = (nb + 3) / 4;         // 4 samples (waves) per 256-thread block
    mlp_pde_kernel<<<blocks, 256, 0, stream>>>(x, W0, b0, W1, b1, W2, b2, W3, b3, out, nb);
}

// Round 3
// 125.406 us; speedup vs baseline: 3.8223x; 3.8223x over previous
//
#include <hip/hip_runtime.h>
#include <math.h>

// GradientLayer: 4->128->128->128->5 tanh MLP; per-sample Jacobian (5x4) and
// Hessians of outputs 0 and 4, combined into 17 outputs.
// Round 3: identical structure to round 2 (bf16 MFMA propagation), plus
// compiler memory fences at every LDS phase boundary. Round 2's failure was a
// TBAA-legal reorder: epilogue float4 LDS stores (pbuf) hoisted above the
// `unsigned` LDS loads of rows 5-14 (distinct TBAA tags -> assumed no-alias),
// clobbering the second-order rows while first-order stayed intact.

namespace {

constexpr int HID = 128;

using bf16x8 = __attribute__((ext_vector_type(8))) short;
using f32x4  = __attribute__((ext_vector_type(4))) float;
typedef unsigned       __attribute__((may_alias)) u32a;
typedef unsigned short __attribute__((may_alias)) u16a;

// compiler-level memory fence: no memory op (incl. LDS) may cross
#define LDS_FENCE() asm volatile("" ::: "memory")

struct OSpec {
    int base, mul, off;
    int a0, a1, a2, m;
    int b0, b1, b2, m2;
    float s1, s2;
};

__constant__ OSpec g_ospec[38] = {
    {0,1,0,   0,45,45,46, 45,45,45,46, 1.f,0.f},   // n
    {1,1,0,   5,45,45,46, 45,45,45,46, 1.f,0.f},   // n_t
    {2,3,0,  10,45,45,46, 45,45,45,46, 1.f,0.f},   // n_grd
    {2,3,1,  15,45,45,46, 45,45,45,46, 1.f,0.f},
    {2,3,2,  20,45,45,46, 45,45,45,46, 1.f,0.f},
    {5,3,0,   1,45,45, 0, 45,45,45,46, 1.f,0.f},   // j = n*v
    {5,3,1,   2,45,45, 0, 45,45,45,46, 1.f,0.f},
    {5,3,2,   3,45,45, 0, 45,45,45,46, 1.f,0.f},
    {8,3,0,  10,15,20, 1, 11,16,21, 0, 1.f,1.f},   // j_div
    {8,3,1,  10,15,20, 2, 12,17,22, 0, 1.f,1.f},
    {8,3,2,  10,15,20, 3, 13,18,23, 0, 1.f,1.f},
    {11,1,0,  4,45,45,46, 45,45,45,46, 1.f,0.f},   // Fi
    {12,3,0, 14,45,45,46, 45,45,45,46, 1.f,0.f},   // Fi_grd
    {12,3,1, 19,45,45,46, 45,45,45,46, 1.f,0.f},
    {12,3,2, 24,45,45,46, 45,45,45,46, 1.f,0.f},
    {15,4,0, 36,37,38,46, 45,45,45,46, 1.f,0.f},   // Fi_lap row sums
    {15,4,1, 39,40,41,46, 45,45,45,46, 1.f,0.f},
    {15,4,2, 40,42,43,46, 45,45,45,46, 1.f,0.f},
    {15,4,3, 41,43,44,46, 45,45,45,46, 1.f,0.f},
    {19,3,0,  1,45,45,46, 45,45,45,46, 1.f,0.f},   // v
    {19,3,1,  2,45,45,46, 45,45,45,46, 1.f,0.f},
    {19,3,2,  3,45,45,46, 45,45,45,46, 1.f,0.f},
    {22,1,0,  5,45,45,46, 45,45,45,46, 1.f,0.f},   // v_t
    {23,3,0,  1,45,45,10, 45,45,45,46, 1.f,0.f},   // v_adv
    {23,3,1,  2,45,45,15, 45,45,45,46, 1.f,0.f},
    {23,3,2,  3,45,45,20, 45,45,45,46, 1.f,0.f},
    {26,1,0, 26,30,33,46, 45,45,45,46, 1.f,0.f},   // v_lap
    {27,3,0, 29,30,31,46, 45,45,45,46, 1.f,0.f},   // v_div_grd
    {27,3,1, 30,32,33,46, 45,45,45,46, 1.f,0.f},
    {27,3,2, 31,33,34,46, 45,45,45,46, 1.f,0.f},
    {30,1,0,  0,45,45,46, 45,45,45,46, 2.f,0.f},   // ro = 2n
    {31,1,0,  5,45,45,46, 45,45,45,46, 2.f,0.f},   // ro_t
    {32,3,0, 10,45,45,46, 45,45,45,46, 2.f,0.f},   // ro_grd
    {32,3,1, 15,45,45,46, 45,45,45,46, 2.f,0.f},
    {32,3,2, 20,45,45,46, 45,45,45,46, 2.f,0.f},
    {35,3,0, 10,15,20, 1, 11,16,21, 0, 2.f,2.f},   // rov_div
    {35,3,1, 10,15,20, 2, 12,17,22, 0, 2.f,2.f},
    {35,3,2, 10,15,20, 3, 13,18,23, 0, 2.f,2.f},
};

__device__ __forceinline__ unsigned short f2bf(float f) {
    union { float f; unsigned u; } v; v.f = f;
    unsigned r = v.u + 0x7FFFu + ((v.u >> 16) & 1u);   // RNE
    return (unsigned short)(r >> 16);
}
__device__ __forceinline__ float bf2f(unsigned short u) {
    union { unsigned u; float f; } v; v.u = ((unsigned)u) << 16; return v.f;
}
__device__ __forceinline__ float tanh_fast(float z) {
    float e = __builtin_amdgcn_exp2f(z * 2.8853900817779268f);
    return 1.0f - 2.0f * __builtin_amdgcn_rcpf(e + 1.0f);
}
// swizzled byte offset inside the per-wave [16][128] bf16 A-buffer
__device__ __forceinline__ int swz(int row, int byte_in_row) {
    return (row * 256 + byte_in_row) ^ ((row & 7) << 4);
}

// ---- pack W1/W2 into B-fragment-ordered bf16 blobs in d_ws -----------------
// lane holds B[k = kt*32 + (lane>>4)*8 + reg][n = nt*16 + (lane&15)]
__global__ void pack_w_kernel(const float* __restrict__ W1,
                              const float* __restrict__ W2,
                              unsigned short* __restrict__ wsB) {
    int t = blockIdx.x * 256 + threadIdx.x;        // 0..32767
    int reg  = t & 7;
    int lane = (t >> 3) & 63;
    int nt   = (t >> 9) & 7;
    int kt   = (t >> 12) & 3;
    int layer = (t >> 14) & 1;
    int k = kt * 32 + (lane >> 4) * 8 + reg;
    int n = nt * 16 + (lane & 15);
    const float* W = layer ? W2 : W1;
    wsB[t] = f2bf(W[k * HID + n]);
}

__global__ __launch_bounds__(256, 4) void mlp_pde_kernel(
    const float* __restrict__ x,
    const float* __restrict__ W0, const float* __restrict__ b0,
    const float* __restrict__ b1, const float* __restrict__ b2,
    const float* __restrict__ W3, const float* __restrict__ b3,
    const unsigned short* __restrict__ wsB,
    float* __restrict__ out, int nb)
{
    constexpr int PD[10] = {0,0,0,0,1,1,1,2,2,3};
    constexpr int PE[10] = {0,1,2,3,1,2,3,2,3,3};

    __shared__ float lds[4][1728];                 // 6912 B per wave
    const int wave = threadIdx.x >> 6;
    const int lane = threadIdx.x & 63;
    char* abuf = (char*)lds[wave];                 // first 4096 B: [16][128] bf16 (swizzled)
    int b = blockIdx.x * 4 + wave;
    if (b >= nb) b = nb - 1;

    // ---------------- layer 0 (4 -> 128), fp32, lane owns cols 2l,2l+1 ------
    {
        const int j0 = lane * 2;
        const float4 xv = *reinterpret_cast<const float4*>(x + 4 * b);
        float w0d[4][2];
        #pragma unroll
        for (int d = 0; d < 4; ++d) {
            float2 w = *reinterpret_cast<const float2*>(W0 + d * HID + j0);
            w0d[d][0] = w.x; w0d[d][1] = w.y;
        }
        const float2 bb0 = *reinterpret_cast<const float2*>(b0 + j0);
        float val[15][2];
        #pragma unroll
        for (int jj = 0; jj < 2; ++jj) {
            float z = ((jj == 0) ? bb0.x : bb0.y)
                    + xv.x * w0d[0][jj] + xv.y * w0d[1][jj]
                    + xv.z * w0d[2][jj] + xv.w * w0d[3][jj];
            float h = tanh_fast(z);
            float s = 1.f - h * h;
            val[0][jj] = h;
            #pragma unroll
            for (int d = 0; d < 4; ++d) val[1 + d][jj] = s * w0d[d][jj];
            #pragma unroll
            for (int p = 0; p < 10; ++p)
                val[5 + p][jj] = -2.f * h * s * w0d[PD[p]][jj] * w0d[PE[p]][jj];
        }
        #pragma unroll
        for (int v = 0; v < 15; ++v) {
            unsigned pk = (unsigned)f2bf(val[v][0]) | ((unsigned)f2bf(val[v][1]) << 16);
            *reinterpret_cast<u32a*>(abuf + swz(v, j0 * 2)) = pk;
        }
        *reinterpret_cast<u32a*>(abuf + swz(15, j0 * 2)) = 0u;  // pad row
    }
    LDS_FENCE();   // layer-0 stores -> afrag reads

    // ---------------- layers 1,2 via MFMA -----------------------------------
    const int jloc = lane & 15;                    // column within 16-wide tile
    const int rgrp = lane >> 4;                    // row group: rows 4r..4r+3
    #pragma unroll 1
    for (int layer = 0; layer < 2; ++layer) {
        // A fragments: lane holds A[m = lane&15][k = kt*32 + (lane>>4)*8 + 0..7]
        bf16x8 afrag[4];
        #pragma unroll
        for (int kt = 0; kt < 4; ++kt)
            afrag[kt] = *reinterpret_cast<const bf16x8*>(
                abuf + (swz(jloc, kt * 64 + rgrp * 16)));
        LDS_FENCE();   // afrag reads -> recombination stores (WAR)
        const float* bias = layer ? b2 : b1;

        #pragma unroll 1
        for (int nt = 0; nt < 8; ++nt) {
            f32x4 acc = {0.f, 0.f, 0.f, 0.f};
            #pragma unroll
            for (int kt = 0; kt < 4; ++kt) {
                bf16x8 bfrag = *reinterpret_cast<const bf16x8*>(
                    wsB + ((size_t)((layer * 4 + kt) * 8 + nt) * 512 + lane * 8));
                acc = __builtin_amdgcn_mfma_f32_16x16x32_bf16(afrag[kt], bfrag, acc, 0, 0, 0);
            }
            // broadcast primal + first-order tangents within the column group
            float z0 = __shfl(acc[0], jloc, 64);         // row 0 (primal z)
            float u0 = __shfl(acc[1], jloc, 64);         // row 1 (dz_0)
            float u1 = __shfl(acc[2], jloc, 64);         // row 2 (dz_1)
            float u2 = __shfl(acc[3], jloc, 64);         // row 3 (dz_2)
            float u3 = __shfl(acc[0], jloc + 16, 64);    // row 4 (dz_3)
            float h = tanh_fast(z0 + bias[nt * 16 + jloc]);
            float s = 1.f - h * h;
            float c = -2.f * h * s;
            float nv[4];
            if (rgrp == 0) {
                nv[0] = h;           nv[1] = s * u0;
                nv[2] = s * u1;      nv[3] = s * u2;
            } else if (rgrp == 1) {
                nv[0] = s * u3;
                nv[1] = fmaf(c * u0, u0, s * acc[1]);    // row 5  (0,0)
                nv[2] = fmaf(c * u0, u1, s * acc[2]);    // row 6  (0,1)
                nv[3] = fmaf(c * u0, u2, s * acc[3]);    // row 7  (0,2)
            } else if (rgrp == 2) {
                nv[0] = fmaf(c * u0, u3, s * acc[0]);    // row 8  (0,3)
                nv[1] = fmaf(c * u1, u1, s * acc[1]);    // row 9  (1,1)
                nv[2] = fmaf(c * u1, u2, s * acc[2]);    // row 10 (1,2)
                nv[3] = fmaf(c * u1, u3, s * acc[3]);    // row 11 (1,3)
            } else {
                nv[0] = fmaf(c * u2, u2, s * acc[0]);    // row 12 (2,2)
                nv[1] = fmaf(c * u2, u3, s * acc[1]);    // row 13 (2,3)
                nv[2] = fmaf(c * u3, u3, s * acc[2]);    // row 14 (3,3)
                nv[3] = 0.f;                             // pad row 15
            }
            #pragma unroll
            for (int q = 0; q < 4; ++q) {
                int mm = rgrp * 4 + q;
                *reinterpret_cast<u16a*>(
                    abuf + swz(mm, (nt * 16 + jloc) * 2)) = f2bf(nv[q]);
            }
        }
        LDS_FENCE();   // recombination stores -> next-layer afrag / epilogue reads
    }

    // ---------------- epilogue: identical math to validated round-1 ---------
    const int j0 = lane * 2;
    float val[15][2];
    #pragma unroll
    for (int v = 0; v < 15; ++v) {
        unsigned u = *reinterpret_cast<const u32a*>(abuf + swz(v, j0 * 2));
        val[v][0] = bf2f((unsigned short)(u & 0xFFFFu));
        val[v][1] = bf2f((unsigned short)(u >> 16));
    }
    LDS_FENCE();   // *** the round-2 bug: val reads must precede pbuf stores ***

    float w3r[2][5];
    #pragma unroll
    for (int k = 0; k < 5; ++k) {
        w3r[0][k] = W3[j0 * 5 + k];
        w3r[1][k] = W3[(j0 + 1) * 5 + k];
    }
    float part[45];
    #pragma unroll
    for (int k = 0; k < 5; ++k)
        part[k] = val[0][0] * w3r[0][k] + val[0][1] * w3r[1][k];
    #pragma unroll
    for (int d = 0; d < 4; ++d) {
        #pragma unroll
        for (int k = 0; k < 5; ++k)
            part[5 + 5 * d + k] = val[1 + d][0] * w3r[0][k] + val[1 + d][1] * w3r[1][k];
    }
    #pragma unroll
    for (int p = 0; p < 10; ++p) {
        part[25 + p] = val[5 + p][0] * w3r[0][0] + val[5 + p][1] * w3r[1][0];
        part[35 + p] = val[5 + p][0] * w3r[0][4] + val[5 + p][1] * w3r[1][4];
    }

    #pragma unroll
    for (int cI = 0; cI < 45; ++cI) part[cI] += __shfl_xor(part[cI], 32, 64);

    float* pbuf = lds[wave];                       // reuse wave region: [32][52]
    if (lane < 32) {
        #pragma unroll
        for (int q = 0; q < 11; ++q)
            *reinterpret_cast<float4*>(&pbuf[lane * 52 + q * 4]) =
                make_float4(part[4 * q], part[4 * q + 1], part[4 * q + 2], part[4 * q + 3]);
        pbuf[lane * 52 + 44] = part[44];
    }
    LDS_FENCE();   // pbuf stores -> comb-phase reads
    float* comb = pbuf + 32 * 52;                  // slots 1664..1710
    if (lane < 47) {
        float t;
        if (lane < 45) {
            t = 0.f;
            for (int l = 0; l < 32; ++l) t += pbuf[l * 52 + lane];
            if (lane < 5) t += b3[lane];
        } else {
            t = (lane == 46) ? 1.f : 0.f;
        }
        comb[lane] = t;
    }
    LDS_FENCE();   // comb stores -> final reads
    if (lane < 38) {
        OSpec sp = g_ospec[lane];
        float t1 = (comb[sp.a0] + comb[sp.a1] + comb[sp.a2]) * comb[sp.m] * sp.s1;
        float t2 = (comb[sp.b0] + comb[sp.b1] + comb[sp.b2]) * comb[sp.m2] * sp.s2;
        out[sp.base * nb + b * sp.mul + sp.off] = t1 + t2;
    }
}

} // namespace

extern "C" void kernel_launch(void* const* d_in, const int* in_sizes, int n_in,
                              void* d_out, int out_size, void* d_ws, size_t ws_size,
                              hipStream_t stream) {
    const float* x  = (const float*)d_in[0];
    const float* W0 = (const float*)d_in[1];
    const float* b0 = (const float*)d_in[2];
    const float* W1 = (const float*)d_in[3];
    const float* b1 = (const float*)d_in[4];
    const float* W2 = (const float*)d_in[5];
    const float* b2 = (const float*)d_in[6];
    const float* W3 = (const float*)d_in[7];
    const float* b3 = (const float*)d_in[8];
    float* out = (float*)d_out;
    unsigned short* wsB = (unsigned short*)d_ws;   // 64 KB used

    const int nb = in_sizes[0] / 4;                // 32768
    pack_w_kernel<<<128, 256, 0, stream>>>(W1, W2, wsB);
    const int blocks = (nb + 3) / 4;
    mlp_pde_kernel<<<blocks, 256, 0, stream>>>(x, W0, b0, b1, b2, W3, b3, wsB, out, nb);
}

// Round 4
// 110.068 us; speedup vs baseline: 4.3549x; 1.1393x over previous
//
#include <hip/hip_runtime.h>
#include <hip/hip_bf16.h>

// GradientLayer: 4->128->128->128->5 tanh MLP; per-sample Jacobian (5x4) and
// Hessians of outputs 0 and 4, combined into 17 outputs.
// Round 4 (from validated round 3):
//  - W3 epilogue replaced by one more MFMA chain (T 16x128 @ W3pad 128x16);
//    results land in comb2[] via the C/D layout; OSpec table index-remapped
//    (Hn: 25+p -> 25+5p, HFi: 35+p -> 29+5p, const slots 80/81).
//  - bf16 conversions via __float22bfloat162_rn (packed cvt path).
//  - LDS per wave 6912 -> 4480 B; __launch_bounds__(256,8) for 8 blocks/CU.

namespace {

constexpr int HID = 128;

using bf16x8 = __attribute__((ext_vector_type(8))) short;
using f32x4  = __attribute__((ext_vector_type(4))) float;
typedef unsigned       __attribute__((may_alias)) u32a;
typedef unsigned short __attribute__((may_alias)) u16a;

#define LDS_FENCE() asm volatile("" ::: "memory")

struct OSpec {
    int base, mul, off;
    int a0, a1, a2, m;
    int b0, b1, b2, m2;
    float s1, s2;
};

// comb2[] indices: value (v,k) at v*5+k, v in 0..14, k in 0..4.
// o_k = comb2[k]; J[k][d] = comb2[(1+d)*5+k] = 5+5d+k (same as round 3);
// Hn[p] = comb2[(5+p)*5+0] = 25+5p; HFi[p] = comb2[(5+p)*5+4] = 29+5p.
// comb2[80] = 0, comb2[81] = 1.
__constant__ OSpec g_ospec[38] = {
    {0,1,0,   0,80,80,81, 80,80,80,81, 1.f,0.f},   // n
    {1,1,0,   5,80,80,81, 80,80,80,81, 1.f,0.f},   // n_t
    {2,3,0,  10,80,80,81, 80,80,80,81, 1.f,0.f},   // n_grd
    {2,3,1,  15,80,80,81, 80,80,80,81, 1.f,0.f},
    {2,3,2,  20,80,80,81, 80,80,80,81, 1.f,0.f},
    {5,3,0,   1,80,80, 0, 80,80,80,81, 1.f,0.f},   // j = n*v
    {5,3,1,   2,80,80, 0, 80,80,80,81, 1.f,0.f},
    {5,3,2,   3,80,80, 0, 80,80,80,81, 1.f,0.f},
    {8,3,0,  10,15,20, 1, 11,16,21, 0, 1.f,1.f},   // j_div
    {8,3,1,  10,15,20, 2, 12,17,22, 0, 1.f,1.f},
    {8,3,2,  10,15,20, 3, 13,18,23, 0, 1.f,1.f},
    {11,1,0,  4,80,80,81, 80,80,80,81, 1.f,0.f},   // Fi
    {12,3,0, 14,80,80,81, 80,80,80,81, 1.f,0.f},   // Fi_grd
    {12,3,1, 19,80,80,81, 80,80,80,81, 1.f,0.f},
    {12,3,2, 24,80,80,81, 80,80,80,81, 1.f,0.f},
    {15,4,0, 34,39,44,81, 80,80,80,81, 1.f,0.f},   // Fi_lap (HFi p=1,2,3)
    {15,4,1, 49,54,59,81, 80,80,80,81, 1.f,0.f},   //        (p=4,5,6)
    {15,4,2, 54,64,69,81, 80,80,80,81, 1.f,0.f},   //        (p=5,7,8)
    {15,4,3, 59,69,74,81, 80,80,80,81, 1.f,0.f},   //        (p=6,8,9)
    {19,3,0,  1,80,80,81, 80,80,80,81, 1.f,0.f},   // v
    {19,3,1,  2,80,80,81, 80,80,80,81, 1.f,0.f},
    {19,3,2,  3,80,80,81, 80,80,80,81, 1.f,0.f},
    {22,1,0,  5,80,80,81, 80,80,80,81, 1.f,0.f},   // v_t
    {23,3,0,  1,80,80,10, 80,80,80,81, 1.f,0.f},   // v_adv
    {23,3,1,  2,80,80,15, 80,80,80,81, 1.f,0.f},
    {23,3,2,  3,80,80,20, 80,80,80,81, 1.f,0.f},
    {26,1,0, 30,50,65,81, 80,80,80,81, 1.f,0.f},   // v_lap (Hn p=1,5,8)
    {27,3,0, 45,50,55,81, 80,80,80,81, 1.f,0.f},   // v_div_grd (p=4,5,6)
    {27,3,1, 50,60,65,81, 80,80,80,81, 1.f,0.f},   //           (p=5,7,8)
    {27,3,2, 55,65,70,81, 80,80,80,81, 1.f,0.f},   //           (p=6,8,9)
    {30,1,0,  0,80,80,81, 80,80,80,81, 2.f,0.f},   // ro = 2n
    {31,1,0,  5,80,80,81, 80,80,80,81, 2.f,0.f},   // ro_t
    {32,3,0, 10,80,80,81, 80,80,80,81, 2.f,0.f},   // ro_grd
    {32,3,1, 15,80,80,81, 80,80,80,81, 2.f,0.f},
    {32,3,2, 20,80,80,81, 80,80,80,81, 2.f,0.f},
    {35,3,0, 10,15,20, 1, 11,16,21, 0, 2.f,2.f},   // rov_div
    {35,3,1, 10,15,20, 2, 12,17,22, 0, 2.f,2.f},
    {35,3,2, 10,15,20, 3, 13,18,23, 0, 2.f,2.f},
};

__device__ __forceinline__ unsigned short f2bf(float f) {
    union { float f; unsigned u; } v; v.f = f;
    unsigned r = v.u + 0x7FFFu + ((v.u >> 16) & 1u);   // RNE
    return (unsigned short)(r >> 16);
}
__device__ __forceinline__ unsigned pk_bf16(float lo, float hi) {
    __hip_bfloat162 h2 = __float22bfloat162_rn(make_float2(lo, hi));
    unsigned r; __builtin_memcpy(&r, &h2, 4); return r;   // lo in bits 0-15
}
__device__ __forceinline__ float tanh_fast(float z) {
    float e = __builtin_amdgcn_exp2f(z * 2.8853900817779268f);
    return 1.0f - 2.0f * __builtin_amdgcn_rcpf(e + 1.0f);
}
// swizzled byte offset inside the per-wave [16][128] bf16 A-buffer
__device__ __forceinline__ int swz(int row, int byte_in_row) {
    return (row * 256 + byte_in_row) ^ ((row & 7) << 4);
}

// ---- pack W1/W2 (+ W3 padded to 16 cols) into B-fragment bf16 in d_ws ------
// W1/W2 region: [layer][kt][nt][lane][reg]; lane holds
//   B[k = kt*32 + (lane>>4)*8 + reg][n = nt*16 + (lane&15)]
// W3 region (base 32768): [kt][lane][reg]; B[k][n] = n<5 ? W3[k][n] : 0
__global__ void pack_w_kernel(const float* __restrict__ W1,
                              const float* __restrict__ W2,
                              const float* __restrict__ W3,
                              unsigned short* __restrict__ wsB) {
    int t = blockIdx.x * 256 + threadIdx.x;        // 0..34815
    if (t < 32768) {
        int reg  = t & 7;
        int lane = (t >> 3) & 63;
        int nt   = (t >> 9) & 7;
        int kt   = (t >> 12) & 3;
        int layer = (t >> 14) & 1;
        int k = kt * 32 + (lane >> 4) * 8 + reg;
        int n = nt * 16 + (lane & 15);
        const float* W = layer ? W2 : W1;
        wsB[t] = f2bf(W[k * HID + n]);
    } else if (t < 34816) {
        int tt = t - 32768;
        int reg  = tt & 7;
        int lane = (tt >> 3) & 63;
        int kt   = (tt >> 9) & 3;
        int k = kt * 32 + (lane >> 4) * 8 + reg;
        int n = lane & 15;
        wsB[t] = (n < 5) ? f2bf(W3[k * 5 + n]) : (unsigned short)0;
    }
}

__global__ __launch_bounds__(256, 8) void mlp_pde_kernel(
    const float* __restrict__ x,
    const float* __restrict__ W0, const float* __restrict__ b0,
    const float* __restrict__ b1, const float* __restrict__ b2,
    const float* __restrict__ b3,
    const unsigned short* __restrict__ wsB,
    float* __restrict__ out, int nb)
{
    constexpr int PD[10] = {0,0,0,0,1,1,1,2,2,3};
    constexpr int PE[10] = {0,1,2,3,1,2,3,2,3,3};

    __shared__ float lds[4][1120];                 // 4480 B per wave, 17920 B/block
    const int wave = threadIdx.x >> 6;
    const int lane = threadIdx.x & 63;
    char* abuf = (char*)lds[wave];                 // first 4096 B: [16][128] bf16 (swizzled)
    int b = blockIdx.x * 4 + wave;
    if (b >= nb) b = nb - 1;

    // ---------------- layer 0 (4 -> 128), fp32, lane owns cols 2l,2l+1 ------
    {
        const int j0 = lane * 2;
        const float4 xv = *reinterpret_cast<const float4*>(x + 4 * b);
        float w0d[4][2];
        #pragma unroll
        for (int d = 0; d < 4; ++d) {
            float2 w = *reinterpret_cast<const float2*>(W0 + d * HID + j0);
            w0d[d][0] = w.x; w0d[d][1] = w.y;
        }
        const float2 bb0 = *reinterpret_cast<const float2*>(b0 + j0);
        float val[15][2];
        #pragma unroll
        for (int jj = 0; jj < 2; ++jj) {
            float z = ((jj == 0) ? bb0.x : bb0.y)
                    + xv.x * w0d[0][jj] + xv.y * w0d[1][jj]
                    + xv.z * w0d[2][jj] + xv.w * w0d[3][jj];
            float h = tanh_fast(z);
            float s = 1.f - h * h;
            val[0][jj] = h;
            #pragma unroll
            for (int d = 0; d < 4; ++d) val[1 + d][jj] = s * w0d[d][jj];
            #pragma unroll
            for (int p = 0; p < 10; ++p)
                val[5 + p][jj] = -2.f * h * s * w0d[PD[p]][jj] * w0d[PE[p]][jj];
        }
        #pragma unroll
        for (int v = 0; v < 15; ++v)
            *reinterpret_cast<u32a*>(abuf + swz(v, j0 * 2)) = pk_bf16(val[v][0], val[v][1]);
        *reinterpret_cast<u32a*>(abuf + swz(15, j0 * 2)) = 0u;  // pad row
    }
    LDS_FENCE();   // layer-0 stores -> afrag reads

    // ---------------- layers 1,2 via MFMA -----------------------------------
    const int jloc = lane & 15;                    // column within 16-wide tile
    const int rgrp = lane >> 4;                    // row group: rows 4r..4r+3
    #pragma unroll 1
    for (int layer = 0; layer < 2; ++layer) {
        // A fragments: lane holds A[m = lane&15][k = kt*32 + (lane>>4)*8 + 0..7]
        bf16x8 afrag[4];
        #pragma unroll
        for (int kt = 0; kt < 4; ++kt)
            afrag[kt] = *reinterpret_cast<const bf16x8*>(
                abuf + (swz(jloc, kt * 64 + rgrp * 16)));
        LDS_FENCE();   // afrag reads -> recombination stores (WAR)
        const float* bias = layer ? b2 : b1;
        float bv[8];
        #pragma unroll
        for (int nt = 0; nt < 8; ++nt) bv[nt] = bias[nt * 16 + jloc];

        #pragma unroll 1
        for (int nt = 0; nt < 8; ++nt) {
            f32x4 acc = {0.f, 0.f, 0.f, 0.f};
            #pragma unroll
            for (int kt = 0; kt < 4; ++kt) {
                bf16x8 bfrag = *reinterpret_cast<const bf16x8*>(
                    wsB + ((size_t)((layer * 4 + kt) * 8 + nt) * 512 + lane * 8));
                acc = __builtin_amdgcn_mfma_f32_16x16x32_bf16(afrag[kt], bfrag, acc, 0, 0, 0);
            }
            // broadcast primal + first-order tangents within the column group
            float z0 = __shfl(acc[0], jloc, 64);         // row 0 (primal z)
            float u0 = __shfl(acc[1], jloc, 64);         // row 1 (dz_0)
            float u1 = __shfl(acc[2], jloc, 64);         // row 2 (dz_1)
            float u2 = __shfl(acc[3], jloc, 64);         // row 3 (dz_2)
            float u3 = __shfl(acc[0], jloc + 16, 64);    // row 4 (dz_3)
            float h = tanh_fast(z0 + bv[nt]);
            float s = 1.f - h * h;
            float c = -2.f * h * s;
            float nv[4];
            if (rgrp == 0) {
                nv[0] = h;           nv[1] = s * u0;
                nv[2] = s * u1;      nv[3] = s * u2;
            } else if (rgrp == 1) {
                nv[0] = s * u3;
                nv[1] = fmaf(c * u0, u0, s * acc[1]);    // row 5  (0,0)
                nv[2] = fmaf(c * u0, u1, s * acc[2]);    // row 6  (0,1)
                nv[3] = fmaf(c * u0, u2, s * acc[3]);    // row 7  (0,2)
            } else if (rgrp == 2) {
                nv[0] = fmaf(c * u0, u3, s * acc[0]);    // row 8  (0,3)
                nv[1] = fmaf(c * u1, u1, s * acc[1]);    // row 9  (1,1)
                nv[2] = fmaf(c * u1, u2, s * acc[2]);    // row 10 (1,2)
                nv[3] = fmaf(c * u1, u3, s * acc[3]);    // row 11 (1,3)
            } else {
                nv[0] = fmaf(c * u2, u2, s * acc[0]);    // row 12 (2,2)
                nv[1] = fmaf(c * u2, u3, s * acc[1]);    // row 13 (2,3)
                nv[2] = fmaf(c * u3, u3, s * acc[2]);    // row 14 (3,3)
                nv[3] = 0.f;                             // pad row 15
            }
            unsigned pk01 = pk_bf16(nv[0], nv[1]);
            unsigned pk23 = pk_bf16(nv[2], nv[3]);
            const int bcol = (nt * 16 + jloc) * 2;
            *reinterpret_cast<u16a*>(abuf + swz(rgrp * 4 + 0, bcol)) = (unsigned short)pk01;
            *reinterpret_cast<u16a*>(abuf + swz(rgrp * 4 + 1, bcol)) = (unsigned short)(pk01 >> 16);
            *reinterpret_cast<u16a*>(abuf + swz(rgrp * 4 + 2, bcol)) = (unsigned short)pk23;
            *reinterpret_cast<u16a*>(abuf + swz(rgrp * 4 + 3, bcol)) = (unsigned short)(pk23 >> 16);
        }
        LDS_FENCE();   // recombination stores -> next-layer / epilogue reads
    }

    // ---------------- epilogue: T(16x128) @ W3pad(128x16) via MFMA ----------
    bf16x8 tfrag[4];
    #pragma unroll
    for (int kt = 0; kt < 4; ++kt)
        tfrag[kt] = *reinterpret_cast<const bf16x8*>(
            abuf + (swz(jloc, kt * 64 + rgrp * 16)));
    LDS_FENCE();

    f32x4 facc = {0.f, 0.f, 0.f, 0.f};
    #pragma unroll
    for (int kt = 0; kt < 4; ++kt) {
        bf16x8 w3f = *reinterpret_cast<const bf16x8*>(
            wsB + 32768 + (size_t)(kt * 64 + lane) * 8);
        facc = __builtin_amdgcn_mfma_f32_16x16x32_bf16(tfrag[kt], w3f, facc, 0, 0, 0);
    }

    float* comb2 = lds[wave] + 1024;               // 82 slots
    if (jloc < 5) {
        #pragma unroll
        for (int q = 0; q < 4; ++q) {
            int row = rgrp * 4 + q;                // = vector index v
            float t = facc[q];
            if (row == 0) t += b3[jloc];
            comb2[row * 5 + jloc] = t;             // rows 0..15 -> slots 0..79
        }
    }
    if (lane == 63) { comb2[80] = 0.f; comb2[81] = 1.f; }
    LDS_FENCE();   // comb2 stores -> table reads

    if (lane < 38) {
        OSpec sp = g_ospec[lane];
        float t1 = (comb2[sp.a0] + comb2[sp.a1] + comb2[sp.a2]) * comb2[sp.m] * sp.s1;
        float t2 = (comb2[sp.b0] + comb2[sp.b1] + comb2[sp.b2]) * comb2[sp.m2] * sp.s2;
        out[sp.base * nb + b * sp.mul + sp.off] = t1 + t2;
    }
}

} // namespace

extern "C" void kernel_launch(void* const* d_in, const int* in_sizes, int n_in,
                              void* d_out, int out_size, void* d_ws, size_t ws_size,
                              hipStream_t stream) {
    const float* x  = (const float*)d_in[0];
    const float* W0 = (const float*)d_in[1];
    const float* b0 = (const float*)d_in[2];
    const float* W1 = (const float*)d_in[3];
    const float* b1 = (const float*)d_in[4];
    const float* W2 = (const float*)d_in[5];
    const float* b2 = (const float*)d_in[6];
    const float* W3 = (const float*)d_in[7];
    const float* b3 = (const float*)d_in[8];
    float* out = (float*)d_out;
    unsigned short* wsB = (unsigned short*)d_ws;   // ~68 KB used

    const int nb = in_sizes[0] / 4;                // 32768
    pack_w_kernel<<<136, 256, 0, stream>>>(W1, W2, W3, wsB);
    const int blocks = (nb + 3) / 4;
    mlp_pde_kernel<<<blocks, 256, 0, stream>>>(x, W0, b0, b1, b2, b3, wsB, out, nb);
}